// Round 9
// baseline (1232.745 us; speedup 1.0000x reference)
//
#include <hip/hip_runtime.h>
#include <math.h>
#include <stdint.h>

// Mamba2-lite mixer, round 9: r8 code with Lc=4096 (single chunk, M=16384).
// Measured: M=16384 squares run 886 TF (r4, trans-epilogue) vs 585 TF at
// M=8192 (r8, poly) -- per-launch fixed costs amortize with M, L3 absorbs
// A re-fetches. Poly epilogues + split XZ + natural dispatch kept from r8.
// B=4, L=4096, Dm=1024, Di=2048, K=4.

#define BATCH 4
#define SEQ 4096
#define DMODEL 1024
#define DINNER 2048
#define CLS 32          // scan sub-chunk length

typedef __bf16 bf16_t;
typedef __bf16 bf16x8 __attribute__((ext_vector_type(8)));
typedef float f32x4 __attribute__((ext_vector_type(4)));
typedef unsigned short ushort_t;
typedef unsigned short u16x4 __attribute__((ext_vector_type(4)));

enum { EP_F32 = 0, EP_BF = 1, EP_SIG = 2, EP_DT = 3, EP_TANH = 4 };

__device__ __forceinline__ void gload_lds16(const void* g, void* l) {
    __builtin_amdgcn_global_load_lds(
        (const __attribute__((address_space(1))) void*)g,
        (__attribute__((address_space(3))) void*)l, 16, 0, 0);
}

__device__ __forceinline__ ushort_t f2bf(float f) {
    union { float f; uint32_t u; } c; c.f = f;
    uint32_t u = c.u;
    u += 0x7fffu + ((u >> 16) & 1u);          // RNE
    return (ushort_t)(u >> 16);
}
__device__ __forceinline__ float bf2f(ushort_t h) {
    union { uint32_t u; float f; } c; c.u = (uint32_t)h << 16;
    return c.f;
}
__device__ __forceinline__ float tanh_exact(float v) {
    v = fminf(fmaxf(v, -15.f), 15.f);
    float e = __expf(2.f * v);
    return (e - 1.f) / (e + 1.f);
}
// tanh: Taylor for |v|<0.25 (err <4e-7), exact fallback (never taken on
// this data: dt/b/c GEMM outputs have std~0.012).
__device__ __forceinline__ float tanh_poly(float v) {
    float v2 = v * v;
    float t = v * (1.f - v2 * (0.33333333f - 0.13333333f * v2));
    if (__builtin_expect(fabsf(v) > 0.25f, 0)) t = tanh_exact(v);
    return t;
}
// softplus: Taylor at 0 for |v|<0.25 (err <1e-8), exact fallback.
__device__ __forceinline__ float softplus_poly(float v) {
    float v2 = v * v;
    float s = 0.69314718f + 0.5f * v + v2 * (0.125f - 0.0052083333f * v2);
    if (__builtin_expect(fabsf(v) > 0.25f, 0))
        s = fmaxf(v, 0.f) + __logf(1.f + __expf(-fabsf(v)));
    return s;
}

// ---------------- bf16 MFMA GEMM with fused epilogues --------------------
// C[m,n] = sum_k A[m,k]*W[n,k]. 128x128 tile, BK=64, 4 waves, 16x16x32
// MFMA, XOR-swizzled LDS via pre-swizzled global source (rule #21).
// NATURAL blockIdx order (r5: XCD-chunk swizzle regressed 4.8x).
#define GBK 64

__global__ __launch_bounds__(256) void gemm_bf16_ep(
    const bf16_t* __restrict__ A, const bf16_t* __restrict__ W,
    const float* __restrict__ bias,
    float* __restrict__ Cf, ushort_t* __restrict__ T0,
    const float* __restrict__ alogp,
    int K, int Nout, int Lc, int a_bstride, int a_l0,
    int c_bstride, int c_l0, int mode)
{
    __shared__ __align__(16) bf16_t sA[128 * GBK];   // 16 KB
    __shared__ __align__(16) bf16_t sB[128 * GBK];   // 16 KB
    const int tid = threadIdx.x;
    const int lane = tid & 63;
    const int wid = tid >> 6;
    const int wm = wid >> 1, wn = wid & 1;
    const int n0 = blockIdx.x * 128;
    const int m0 = blockIdx.y * 128;
    const int bb = m0 / Lc;
    const int lb = m0 - bb * Lc;
    const bf16_t* Abase = A + ((size_t)bb * a_bstride + a_l0 + lb) * K;
    const bf16_t* Wbase = W + (size_t)n0 * K;

    int st_row[4], st_sc[4], st_ofs[4];
#pragma unroll
    for (int i = 0; i < 4; ++i) {
        int ofs = tid * 16 + i * 4096;
        int r = ofs >> 7;
        int c16 = (ofs >> 4) & 7;
        st_ofs[i] = ofs;
        st_row[i] = r;
        st_sc[i] = (c16 ^ (r & 7)) << 3;
    }

    f32x4 acc[4][4];
#pragma unroll
    for (int i = 0; i < 4; ++i)
#pragma unroll
        for (int j = 0; j < 4; ++j) acc[i][j] = f32x4{0.f, 0.f, 0.f, 0.f};

    for (int k0 = 0; k0 < K; k0 += GBK) {
#pragma unroll
        for (int i = 0; i < 4; ++i) {
            gload_lds16(Abase + (size_t)st_row[i] * K + k0 + st_sc[i],
                        (char*)sA + st_ofs[i]);
            gload_lds16(Wbase + (size_t)st_row[i] * K + k0 + st_sc[i],
                        (char*)sB + st_ofs[i]);
        }
        __syncthreads();
#pragma unroll
        for (int ks = 0; ks < 2; ++ks) {
            bf16x8 av[4], bv[4];
#pragma unroll
            for (int mi = 0; mi < 4; ++mi) {
                int row = wm * 64 + mi * 16 + (lane & 15);
                int cb = (ks * 64 + ((lane >> 4) << 4)) ^ ((row & 7) << 4);
                av[mi] = *(const bf16x8*)((const char*)sA + row * 128 + cb);
            }
#pragma unroll
            for (int ni = 0; ni < 4; ++ni) {
                int row = wn * 64 + ni * 16 + (lane & 15);
                int cb = (ks * 64 + ((lane >> 4) << 4)) ^ ((row & 7) << 4);
                bv[ni] = *(const bf16x8*)((const char*)sB + row * 128 + cb);
            }
#pragma unroll
            for (int mi = 0; mi < 4; ++mi)
#pragma unroll
                for (int ni = 0; ni < 4; ++ni)
                    acc[mi][ni] = __builtin_amdgcn_mfma_f32_16x16x32_bf16(
                        av[mi], bv[ni], acc[mi][ni], 0, 0, 0);
        }
        __syncthreads();
    }

    // ---- fused epilogue ----
    const size_t rowbase = (size_t)bb * c_bstride + c_l0 + lb;
#pragma unroll
    for (int ni = 0; ni < 4; ++ni) {
        const int coll = wn * 64 + ni * 16 + (lane & 15);
        float bv = bias ? bias[n0 + coll] : 0.f;
        const float Ae = (mode == EP_DT) ? __expf(alogp[n0 + coll]) : 0.f;
#pragma unroll
        for (int mi = 0; mi < 4; ++mi) {
#pragma unroll
            for (int r4 = 0; r4 < 4; ++r4) {
                const int rowl = wm * 64 + mi * 16 + ((lane >> 4) << 2) + r4;
                const size_t off = (rowbase + rowl) * (size_t)Nout + n0 + coll;
                float v = acc[mi][ni][r4] + bv;
                if (mode == EP_F32) {
                    Cf[off] = v;
                } else if (mode == EP_BF) {
                    T0[off] = f2bf(v);
                } else if (mode == EP_SIG) {
                    T0[off] = f2bf(1.f / (1.f + __expf(-v)));
                } else if (mode == EP_DT) {
                    float sp = softplus_poly(v);
                    T0[off] = f2bf(__expf(-(sp + 1e-4f) * Ae));   // decay
                } else {  // EP_TANH
                    T0[off] = f2bf(tanh_poly(v));                 // bt/ct
                }
            }
        }
    }
}

// ---------------- f32 -> bf16 conversion (one-time) ----------------------
__global__ __launch_bounds__(256) void cvt_bf16_k(
    const float4* __restrict__ in, ushort4* __restrict__ out, int n4)
{
    for (int i = blockIdx.x * 256 + threadIdx.x; i < n4; i += gridDim.x * 256) {
        float4 v = in[i];
        ushort4 o;
        o.x = f2bf(v.x); o.y = f2bf(v.y); o.z = f2bf(v.z); o.w = f2bf(v.w);
        out[i] = o;
    }
}

// ---------------- causal depthwise conv1d (k=4) + SiLU, bf16 ------------
__global__ __launch_bounds__(256) void conv_silu_bf(
    const ushort_t* __restrict__ xb, const ushort_t* __restrict__ tailb,
    const float* __restrict__ cw, const float* __restrict__ cb,
    ushort_t* __restrict__ ubf, int Lc, int l0, size_t total)
{
    for (size_t idx = (size_t)blockIdx.x * 256 + threadIdx.x; idx < total;
         idx += (size_t)gridDim.x * 256) {
        int e = (int)(idx % DINNER);
        size_t r = idx / DINNER;
        int lp = (int)(r % Lc);
        int b  = (int)(r / Lc);
        float4 w = *(const float4*)(cw + (size_t)e * 4);
        float s = cb[e];
        const ushort_t* xbase = xb + (size_t)b * Lc * DINNER + e;
        if (lp >= 3) {
            s += bf2f(xbase[(size_t)(lp - 3) * DINNER]) * w.x
               + bf2f(xbase[(size_t)(lp - 2) * DINNER]) * w.y
               + bf2f(xbase[(size_t)(lp - 1) * DINNER]) * w.z
               + bf2f(xbase[(size_t)lp * DINNER]) * w.w;
        } else {
            const float ws4[4] = {w.x, w.y, w.z, w.w};
            const ushort_t* tbase = tailb + (size_t)b * 3 * DINNER + e;
#pragma unroll
            for (int j = 0; j < 4; ++j) {
                int ls = lp - 3 + j;
                float v;
                if (ls >= 0)            v = bf2f(xbase[(size_t)ls * DINNER]);
                else if (l0 + ls >= 0)  v = bf2f(tbase[(size_t)(3 + ls) * DINNER]);
                else                    v = 0.f;
                s += v * ws4[j];
            }
        }
        ubf[idx] = f2bf(s / (1.f + __expf(-s)));
    }
}

__global__ __launch_bounds__(256) void tail_update_bf(
    const ushort_t* __restrict__ xb, ushort_t* __restrict__ tailb, int Lc)
{
    int idx = blockIdx.x * 256 + threadIdx.x;     // BATCH*3*DINNER
    if (idx >= BATCH * 3 * DINNER) return;
    int e = idx % DINNER;
    int j = (idx / DINNER) % 3;
    int b = idx / (3 * DINNER);
    tailb[idx] = xb[((size_t)b * Lc + Lc - 3 + j) * DINNER + e];
}

// ---------------- scan phase1: inc=(1-d)*bt*u on the fly, x4 ------------
__global__ __launch_bounds__(256) void scan1_v4(
    const ushort_t* __restrict__ dec, const ushort_t* __restrict__ bt,
    const ushort_t* __restrict__ ub,
    float* __restrict__ P, float* __restrict__ S, int Lc, int nsub)
{
    int t = blockIdx.x * 256 + threadIdx.x;    // BATCH*nsub*512 threads
    int e = (t & 511) << 2;
    int rest = t >> 9;
    int c = rest % nsub;
    int b = rest / nsub;
    size_t off = ((size_t)b * Lc + (size_t)c * CLS) * DINNER + e;
    float p[4] = {1.f, 1.f, 1.f, 1.f};
    float s[4] = {0.f, 0.f, 0.f, 0.f};
    for (int t0 = 0; t0 < CLS; ++t0) {
        size_t o = off + (size_t)t0 * DINNER;
        u16x4 d4 = *(const u16x4*)(dec + o);
        u16x4 b4 = *(const u16x4*)(bt + o);
        u16x4 u4 = *(const u16x4*)(ub + o);
#pragma unroll
        for (int j = 0; j < 4; ++j) {
            float d = bf2f(d4[j]);
            float inc = (1.f - d) * bf2f(b4[j]) * bf2f(u4[j]);
            s[j] = d * s[j] + inc;
            p[j] *= d;
        }
    }
    size_t po = ((size_t)b * nsub + c) * DINNER + e;
    *(float4*)(P + po) = float4{p[0], p[1], p[2], p[3]};
    *(float4*)(S + po) = float4{s[0], s[1], s[2], s[3]};
}

// ---------------- scan phase2: sequential combine over sub-chunks -------
__global__ __launch_bounds__(256) void scan_p2(
    float* __restrict__ P, float* __restrict__ S,
    float* __restrict__ carry, int nsub, int first)
{
    int idx = blockIdx.x * 256 + threadIdx.x;   // BATCH*DINNER
    int e = idx % DINNER;
    int b = idx / DINNER;
    float cv = first ? 0.f : carry[idx];
    for (int c = 0; c < nsub; ++c) {
        size_t o = ((size_t)b * nsub + c) * DINNER + e;
        float p = P[o], s = S[o];
        P[o] = cv;
        cv = p * cv + s;
    }
    carry[idx] = cv;
}

// ---------------- phase3 fused: replay + y=(ct*st+D*u)*sig -> bf16 ------
// bt buffer is overwritten in place with ybf.
__global__ __launch_bounds__(256) void p3y_v4(
    const ushort_t* __restrict__ dec, ushort_t* __restrict__ bty,
    const ushort_t* __restrict__ ct, const ushort_t* __restrict__ ub,
    const ushort_t* __restrict__ sg, const float* __restrict__ Dp,
    const float* __restrict__ Pc, int Lc, int nsub)
{
    int t = blockIdx.x * 256 + threadIdx.x;    // BATCH*nsub*512 threads
    int e = (t & 511) << 2;
    int rest = t >> 9;
    int c = rest % nsub;
    int b = rest / nsub;
    size_t off = ((size_t)b * Lc + (size_t)c * CLS) * DINNER + e;
    size_t po = ((size_t)b * nsub + c) * DINNER + e;
    float4 stv = *(const float4*)(Pc + po);
    float4 Dv  = *(const float4*)(Dp + e);
    float st[4] = {stv.x, stv.y, stv.z, stv.w};
    float D4[4] = {Dv.x, Dv.y, Dv.z, Dv.w};
    for (int t0 = 0; t0 < CLS; ++t0) {
        size_t o = off + (size_t)t0 * DINNER;
        u16x4 d4 = *(const u16x4*)(dec + o);
        u16x4 b4 = *(const u16x4*)(bty + o);
        u16x4 c4 = *(const u16x4*)(ct + o);
        u16x4 u4 = *(const u16x4*)(ub + o);
        u16x4 g4 = *(const u16x4*)(sg + o);
        u16x4 y4;
#pragma unroll
        for (int j = 0; j < 4; ++j) {
            float d = bf2f(d4[j]);
            float u = bf2f(u4[j]);
            float inc = (1.f - d) * bf2f(b4[j]) * u;
            st[j] = d * st[j] + inc;
            float y = bf2f(c4[j]) * st[j] + D4[j] * u;
            y4[j] = f2bf(y * bf2f(g4[j]));
        }
        *(u16x4*)(bty + o) = y4;
    }
}

extern "C" void kernel_launch(void* const* d_in, const int* in_sizes, int n_in,
                              void* d_out, int out_size, void* d_ws, size_t ws_size,
                              hipStream_t stream)
{
    const float* x    = (const float*)d_in[0];
    const float* ipw  = (const float*)d_in[1];
    const float* ipb  = (const float*)d_in[2];
    const float* cw   = (const float*)d_in[3];
    const float* cb   = (const float*)d_in[4];
    const float* dtw  = (const float*)d_in[5];
    const float* dtb  = (const float*)d_in[6];
    const float* bw   = (const float*)d_in[7];
    const float* cwt  = (const float*)d_in[8];
    const float* alog = (const float*)d_in[9];
    const float* dpar = (const float*)d_in[10];
    const float* ow   = (const float*)d_in[11];
    const float* ob   = (const float*)d_in[12];
    float* out = (float*)d_out;

    const size_t XN   = (size_t)BATCH * SEQ * DMODEL;
    const size_t WIP  = (size_t)2 * DINNER * DMODEL;
    const size_t WSQ  = (size_t)DINNER * DINNER;
    const size_t WOUT = (size_t)DMODEL * DINNER;
    const size_t const_bytes = 2 * (XN + WIP + 3 * WSQ + WOUT);

    // ---- choose Lc: prefer 4096 (single chunk; M=16384 amortizes best) ----
    const int cands[6] = {4096, 2048, 1024, 512, 256, 128};
    int Lc = 128;
    for (int i = 0; i < 6; ++i) {
        size_t NBe = (size_t)BATCH * cands[i] * DINNER;
        size_t need = const_bytes
                    + 5 * NBe * 2
                    + (size_t)BATCH * 3 * DINNER * 2
                    + (size_t)BATCH * DINNER * 4
                    + 2 * (size_t)BATCH * (cands[i] / CLS) * DINNER * 4
                    + 1024;
        if (need <= ws_size) { Lc = cands[i]; break; }
    }
    const int nsub = Lc / CLS;
    const size_t NBe = (size_t)BATCH * Lc * DINNER;

    // ---- workspace layout ----
    char* p = (char*)d_ws;
    ushort_t* xbf   = (ushort_t*)p; p += XN * 2;
    ushort_t* ipwbf = (ushort_t*)p; p += WIP * 2;
    ushort_t* dtwbf = (ushort_t*)p; p += WSQ * 2;
    ushort_t* bwbf  = (ushort_t*)p; p += WSQ * 2;
    ushort_t* cwtbf = (ushort_t*)p; p += WSQ * 2;
    ushort_t* owbf  = (ushort_t*)p; p += WOUT * 2;
    ushort_t* S1 = (ushort_t*)p; p += NBe * 2;   // xb -> ct
    ushort_t* S2 = (ushort_t*)p; p += NBe * 2;   // u
    ushort_t* S3 = (ushort_t*)p; p += NBe * 2;   // decay
    ushort_t* S4 = (ushort_t*)p; p += NBe * 2;   // bt -> ybf
    ushort_t* S5 = (ushort_t*)p; p += NBe * 2;   // sigmoid(z)
    ushort_t* tailb = (ushort_t*)p; p += (size_t)BATCH * 3 * DINNER * 2;
    float* carry = (float*)p; p += (size_t)BATCH * DINNER * 4;
    float* Pb    = (float*)p; p += (size_t)BATCH * nsub * DINNER * 4;
    float* Sb    = (float*)p;

    const dim3 blk(256);
    const int M = BATCH * Lc;
    const dim3 gSq(DINNER / 128, M / 128);
    const dim3 gOut(DMODEL / 128, M / 128);
    const int pwBlocks = (int)(((NBe + 255) / 256 < 4096) ? (NBe + 255) / 256 : 4096);
    const int scanBlocks = BATCH * nsub * 2;     // x4 vectorized, 512 thr/(b,c)

    auto cvt = [&](const float* in, ushort_t* outp, size_t n) {
        int n4 = (int)(n / 4);
        int g = n4 / 256 < 2048 ? (n4 + 255) / 256 : 2048;
        cvt_bf16_k<<<g, blk, 0, stream>>>((const float4*)in, (ushort4*)outp, n4);
    };
    cvt(x, xbf, XN);
    cvt(ipw, ipwbf, WIP);
    cvt(dtw, dtwbf, WSQ);
    cvt(bw, bwbf, WSQ);
    cvt(cwt, cwtbf, WSQ);
    cvt(ow, owbf, WOUT);

    const int nchunks = SEQ / Lc;
    for (int c = 0; c < nchunks; ++c) {
        const int l0 = c * Lc;
        // 1a. xb = x @ ipw[0:2048]^T + b  (bf16)
        gemm_bf16_ep<<<gSq, blk, 0, stream>>>(
            (const bf16_t*)xbf, (const bf16_t*)ipwbf, ipb,
            nullptr, S1, nullptr,
            DMODEL, DINNER, Lc, SEQ, l0, Lc, 0, EP_BF);
        // 1b. sig = sigmoid(x @ ipw[2048:4096]^T + b)
        gemm_bf16_ep<<<gSq, blk, 0, stream>>>(
            (const bf16_t*)xbf, (const bf16_t*)(ipwbf + (size_t)DINNER * DMODEL),
            ipb + DINNER, nullptr, S5, nullptr,
            DMODEL, DINNER, Lc, SEQ, l0, Lc, 0, EP_SIG);
        // 2. u = silu(conv(xb))
        conv_silu_bf<<<pwBlocks, blk, 0, stream>>>(S1, tailb, cw, cb, S2, Lc, l0, NBe);
        if (nchunks > 1)
            tail_update_bf<<<BATCH * 3 * DINNER / 256, blk, 0, stream>>>(S1, tailb, Lc);
        // 3a. decay = exp(-(softplus_poly(u@dtw+dtb)+1e-4)*A)
        gemm_bf16_ep<<<gSq, blk, 0, stream>>>(
            (const bf16_t*)S2, (const bf16_t*)dtwbf, dtb,
            nullptr, S3, alog,
            DINNER, DINNER, Lc, Lc, 0, Lc, 0, EP_DT);
        // 3b. bt = tanh_poly(u@bw)
        gemm_bf16_ep<<<gSq, blk, 0, stream>>>(
            (const bf16_t*)S2, (const bf16_t*)bwbf, nullptr,
            nullptr, S4, nullptr,
            DINNER, DINNER, Lc, Lc, 0, Lc, 0, EP_TANH);
        // 3c. ct = tanh_poly(u@cw)
        gemm_bf16_ep<<<gSq, blk, 0, stream>>>(
            (const bf16_t*)S2, (const bf16_t*)cwtbf, nullptr,
            nullptr, S1, nullptr,
            DINNER, DINNER, Lc, Lc, 0, Lc, 0, EP_TANH);
        // 4-5. scan partials + combine (inc computed on the fly)
        scan1_v4<<<scanBlocks, blk, 0, stream>>>(S3, S4, S2, Pb, Sb, Lc, nsub);
        scan_p2<<<BATCH * DINNER / 256, blk, 0, stream>>>(Pb, Sb, carry, nsub, c == 0);
        // 6. replay + y = (ct*st + D*u)*sig -> ybf (in place over S4)
        p3y_v4<<<scanBlocks, blk, 0, stream>>>(S3, S4, S1, S2, S5, dpar, Pb, Lc, nsub);
        // 7. out = ybf @ ow^T + ob  (f32)
        gemm_bf16_ep<<<gOut, blk, 0, stream>>>(
            (const bf16_t*)S4, (const bf16_t*)owbf, ob,
            out, nullptr, nullptr,
            DINNER, DMODEL, Lc, Lc, 0, SEQ, l0, EP_F32);
    }
}

// Round 10
// 1121.535 us; speedup vs baseline: 1.0992x; 1.0992x over previous
//
#include <hip/hip_runtime.h>
#include <math.h>
#include <stdint.h>

// Mamba2-lite mixer, round 10: LDS-staged bf16 epilogue stores.
// Diagnosis: bf16 epilogues emitted 32B/wave store segments -> partial-line
// write-allocate RMW fetches (+~100MB HBM per GEMM; r3 f32-writes 51us/70MB
// vs r8 bf16-writes 117us/139MB, same shape). Staging the C-tile through
// LDS and storing 16B/lane contiguous restores full-line writes.
// Everything else = r8 (poly epilogues, split XZ, natural dispatch, Lc<=2048).
// B=4, L=4096, Dm=1024, Di=2048, K=4.

#define BATCH 4
#define SEQ 4096
#define DMODEL 1024
#define DINNER 2048
#define CLS 32          // scan sub-chunk length

typedef __bf16 bf16_t;
typedef __bf16 bf16x8 __attribute__((ext_vector_type(8)));
typedef float f32x4 __attribute__((ext_vector_type(4)));
typedef unsigned short ushort_t;
typedef unsigned short u16x4 __attribute__((ext_vector_type(4)));

enum { EP_F32 = 0, EP_BF = 1, EP_SIG = 2, EP_DT = 3, EP_TANH = 4 };

__device__ __forceinline__ void gload_lds16(const void* g, void* l) {
    __builtin_amdgcn_global_load_lds(
        (const __attribute__((address_space(1))) void*)g,
        (__attribute__((address_space(3))) void*)l, 16, 0, 0);
}

__device__ __forceinline__ ushort_t f2bf(float f) {
    union { float f; uint32_t u; } c; c.f = f;
    uint32_t u = c.u;
    u += 0x7fffu + ((u >> 16) & 1u);          // RNE
    return (ushort_t)(u >> 16);
}
__device__ __forceinline__ float bf2f(ushort_t h) {
    union { uint32_t u; float f; } c; c.u = (uint32_t)h << 16;
    return c.f;
}
__device__ __forceinline__ float tanh_exact(float v) {
    v = fminf(fmaxf(v, -15.f), 15.f);
    float e = __expf(2.f * v);
    return (e - 1.f) / (e + 1.f);
}
// tanh: Taylor for |v|<0.25 (err <4e-7), exact fallback (data: std~0.012).
__device__ __forceinline__ float tanh_poly(float v) {
    float v2 = v * v;
    float t = v * (1.f - v2 * (0.33333333f - 0.13333333f * v2));
    if (__builtin_expect(fabsf(v) > 0.25f, 0)) t = tanh_exact(v);
    return t;
}
// softplus: Taylor at 0 for |v|<0.25 (err <1e-8), exact fallback.
__device__ __forceinline__ float softplus_poly(float v) {
    float v2 = v * v;
    float s = 0.69314718f + 0.5f * v + v2 * (0.125f - 0.0052083333f * v2);
    if (__builtin_expect(fabsf(v) > 0.25f, 0))
        s = fmaxf(v, 0.f) + __logf(1.f + __expf(-fabsf(v)));
    return s;
}

// ---------------- bf16 MFMA GEMM with fused epilogues --------------------
// C[m,n] = sum_k A[m,k]*W[n,k]. 128x128 tile, BK=64, 4 waves, 16x16x32
// MFMA, XOR-swizzled LDS via pre-swizzled global source (rule #21).
// NATURAL blockIdx order (r5: XCD-chunk swizzle regressed 4.8x).
// bf16 outputs go through an LDS-staged transpose so global stores are
// 16B/lane contiguous (full 128B lines, no write-allocate RMW fetch).
#define GBK 64

__global__ __launch_bounds__(256) void gemm_bf16_ep(
    const bf16_t* __restrict__ A, const bf16_t* __restrict__ W,
    const float* __restrict__ bias,
    float* __restrict__ Cf, ushort_t* __restrict__ T0,
    const float* __restrict__ alogp,
    int K, int Nout, int Lc, int a_bstride, int a_l0,
    int c_bstride, int c_l0, int mode)
{
    __shared__ __align__(16) bf16_t smem[128 * 128];   // 32 KB: sA | sB
    bf16_t* sA = smem;
    bf16_t* sB = smem + 128 * GBK;
    const int tid = threadIdx.x;
    const int lane = tid & 63;
    const int wid = tid >> 6;
    const int wm = wid >> 1, wn = wid & 1;
    const int n0 = blockIdx.x * 128;
    const int m0 = blockIdx.y * 128;
    const int bb = m0 / Lc;
    const int lb = m0 - bb * Lc;
    const bf16_t* Abase = A + ((size_t)bb * a_bstride + a_l0 + lb) * K;
    const bf16_t* Wbase = W + (size_t)n0 * K;

    int st_row[4], st_sc[4], st_ofs[4];
#pragma unroll
    for (int i = 0; i < 4; ++i) {
        int ofs = tid * 16 + i * 4096;
        int r = ofs >> 7;
        int c16 = (ofs >> 4) & 7;
        st_ofs[i] = ofs;
        st_row[i] = r;
        st_sc[i] = (c16 ^ (r & 7)) << 3;
    }

    f32x4 acc[4][4];
#pragma unroll
    for (int i = 0; i < 4; ++i)
#pragma unroll
        for (int j = 0; j < 4; ++j) acc[i][j] = f32x4{0.f, 0.f, 0.f, 0.f};

    for (int k0 = 0; k0 < K; k0 += GBK) {
#pragma unroll
        for (int i = 0; i < 4; ++i) {
            gload_lds16(Abase + (size_t)st_row[i] * K + k0 + st_sc[i],
                        (char*)sA + st_ofs[i]);
            gload_lds16(Wbase + (size_t)st_row[i] * K + k0 + st_sc[i],
                        (char*)sB + st_ofs[i]);
        }
        __syncthreads();
#pragma unroll
        for (int ks = 0; ks < 2; ++ks) {
            bf16x8 av[4], bv[4];
#pragma unroll
            for (int mi = 0; mi < 4; ++mi) {
                int row = wm * 64 + mi * 16 + (lane & 15);
                int cb = (ks * 64 + ((lane >> 4) << 4)) ^ ((row & 7) << 4);
                av[mi] = *(const bf16x8*)((const char*)sA + row * 128 + cb);
            }
#pragma unroll
            for (int ni = 0; ni < 4; ++ni) {
                int row = wn * 64 + ni * 16 + (lane & 15);
                int cb = (ks * 64 + ((lane >> 4) << 4)) ^ ((row & 7) << 4);
                bv[ni] = *(const bf16x8*)((const char*)sB + row * 128 + cb);
            }
#pragma unroll
            for (int mi = 0; mi < 4; ++mi)
#pragma unroll
                for (int ni = 0; ni < 4; ++ni)
                    acc[mi][ni] = __builtin_amdgcn_mfma_f32_16x16x32_bf16(
                        av[mi], bv[ni], acc[mi][ni], 0, 0, 0);
        }
        __syncthreads();
    }

    const size_t rowbase = (size_t)bb * c_bstride + c_l0 + lb;
    if (mode == EP_F32) {
        // f32 direct stores (64B/wave segments -- measured full-rate in r3)
#pragma unroll
        for (int ni = 0; ni < 4; ++ni) {
            const int coll = wn * 64 + ni * 16 + (lane & 15);
            const float bv = bias ? bias[n0 + coll] : 0.f;
#pragma unroll
            for (int mi = 0; mi < 4; ++mi) {
#pragma unroll
                for (int r4 = 0; r4 < 4; ++r4) {
                    const int rowl = wm * 64 + mi * 16 + ((lane >> 4) << 2) + r4;
                    Cf[(rowbase + rowl) * (size_t)Nout + n0 + coll] =
                        acc[mi][ni][r4] + bv;
                }
            }
        }
    } else {
        // bf16 modes: transform in regs, stage tile in LDS, store 16B/lane.
        ushort_t* sm = (ushort_t*)smem;
#pragma unroll
        for (int ni = 0; ni < 4; ++ni) {
            const int coll = wn * 64 + ni * 16 + (lane & 15);
            const float bv = bias ? bias[n0 + coll] : 0.f;
            const float Ae = (mode == EP_DT) ? __expf(alogp[n0 + coll]) : 0.f;
#pragma unroll
            for (int mi = 0; mi < 4; ++mi) {
#pragma unroll
                for (int r4 = 0; r4 < 4; ++r4) {
                    const int rowl = wm * 64 + mi * 16 + ((lane >> 4) << 2) + r4;
                    float v = acc[mi][ni][r4] + bv;
                    ushort_t o;
                    if (mode == EP_BF)       o = f2bf(v);
                    else if (mode == EP_SIG) o = f2bf(1.f / (1.f + __expf(-v)));
                    else if (mode == EP_DT)
                        o = f2bf(__expf(-(softplus_poly(v) + 1e-4f) * Ae));
                    else                     o = f2bf(tanh_poly(v));
                    sm[rowl * 128 + coll] = o;
                }
            }
        }
        __syncthreads();
#pragma unroll
        for (int it = 0; it < 8; ++it) {
            const int e = tid * 8 + it * 2048;    // bf16-unit offset in tile
            const int row = e >> 7;
            const int col = e & 127;
            int4 vv = *(const int4*)(sm + e);     // 16B, aligned
            *(int4*)(T0 + (rowbase + row) * (size_t)Nout + n0 + col) = vv;
        }
    }
}

// ---------------- f32 -> bf16 conversion (one-time) ----------------------
__global__ __launch_bounds__(256) void cvt_bf16_k(
    const float4* __restrict__ in, ushort4* __restrict__ out, int n4)
{
    for (int i = blockIdx.x * 256 + threadIdx.x; i < n4; i += gridDim.x * 256) {
        float4 v = in[i];
        ushort4 o;
        o.x = f2bf(v.x); o.y = f2bf(v.y); o.z = f2bf(v.z); o.w = f2bf(v.w);
        out[i] = o;
    }
}

// ---------------- causal depthwise conv1d (k=4) + SiLU, bf16 ------------
__global__ __launch_bounds__(256) void conv_silu_bf(
    const ushort_t* __restrict__ xb, const ushort_t* __restrict__ tailb,
    const float* __restrict__ cw, const float* __restrict__ cb,
    ushort_t* __restrict__ ubf, int Lc, int l0, size_t total)
{
    for (size_t idx = (size_t)blockIdx.x * 256 + threadIdx.x; idx < total;
         idx += (size_t)gridDim.x * 256) {
        int e = (int)(idx % DINNER);
        size_t r = idx / DINNER;
        int lp = (int)(r % Lc);
        int b  = (int)(r / Lc);
        float4 w = *(const float4*)(cw + (size_t)e * 4);
        float s = cb[e];
        const ushort_t* xbase = xb + (size_t)b * Lc * DINNER + e;
        if (lp >= 3) {
            s += bf2f(xbase[(size_t)(lp - 3) * DINNER]) * w.x
               + bf2f(xbase[(size_t)(lp - 2) * DINNER]) * w.y
               + bf2f(xbase[(size_t)(lp - 1) * DINNER]) * w.z
               + bf2f(xbase[(size_t)lp * DINNER]) * w.w;
        } else {
            const float ws4[4] = {w.x, w.y, w.z, w.w};
            const ushort_t* tbase = tailb + (size_t)b * 3 * DINNER + e;
#pragma unroll
            for (int j = 0; j < 4; ++j) {
                int ls = lp - 3 + j;
                float v;
                if (ls >= 0)            v = bf2f(xbase[(size_t)ls * DINNER]);
                else if (l0 + ls >= 0)  v = bf2f(tbase[(size_t)(3 + ls) * DINNER]);
                else                    v = 0.f;
                s += v * ws4[j];
            }
        }
        ubf[idx] = f2bf(s / (1.f + __expf(-s)));
    }
}

__global__ __launch_bounds__(256) void tail_update_bf(
    const ushort_t* __restrict__ xb, ushort_t* __restrict__ tailb, int Lc)
{
    int idx = blockIdx.x * 256 + threadIdx.x;     // BATCH*3*DINNER
    if (idx >= BATCH * 3 * DINNER) return;
    int e = idx % DINNER;
    int j = (idx / DINNER) % 3;
    int b = idx / (3 * DINNER);
    tailb[idx] = xb[((size_t)b * Lc + Lc - 3 + j) * DINNER + e];
}

// ---------------- scan phase1: inc=(1-d)*bt*u on the fly, x4 ------------
__global__ __launch_bounds__(256) void scan1_v4(
    const ushort_t* __restrict__ dec, const ushort_t* __restrict__ bt,
    const ushort_t* __restrict__ ub,
    float* __restrict__ P, float* __restrict__ S, int Lc, int nsub)
{
    int t = blockIdx.x * 256 + threadIdx.x;    // BATCH*nsub*512 threads
    int e = (t & 511) << 2;
    int rest = t >> 9;
    int c = rest % nsub;
    int b = rest / nsub;
    size_t off = ((size_t)b * Lc + (size_t)c * CLS) * DINNER + e;
    float p[4] = {1.f, 1.f, 1.f, 1.f};
    float s[4] = {0.f, 0.f, 0.f, 0.f};
    for (int t0 = 0; t0 < CLS; ++t0) {
        size_t o = off + (size_t)t0 * DINNER;
        u16x4 d4 = *(const u16x4*)(dec + o);
        u16x4 b4 = *(const u16x4*)(bt + o);
        u16x4 u4 = *(const u16x4*)(ub + o);
#pragma unroll
        for (int j = 0; j < 4; ++j) {
            float d = bf2f(d4[j]);
            float inc = (1.f - d) * bf2f(b4[j]) * bf2f(u4[j]);
            s[j] = d * s[j] + inc;
            p[j] *= d;
        }
    }
    size_t po = ((size_t)b * nsub + c) * DINNER + e;
    *(float4*)(P + po) = float4{p[0], p[1], p[2], p[3]};
    *(float4*)(S + po) = float4{s[0], s[1], s[2], s[3]};
}

// ---------------- scan phase2: sequential combine over sub-chunks -------
__global__ __launch_bounds__(256) void scan_p2(
    float* __restrict__ P, float* __restrict__ S,
    float* __restrict__ carry, int nsub, int first)
{
    int idx = blockIdx.x * 256 + threadIdx.x;   // BATCH*DINNER
    int e = idx % DINNER;
    int b = idx / DINNER;
    float cv = first ? 0.f : carry[idx];
    for (int c = 0; c < nsub; ++c) {
        size_t o = ((size_t)b * nsub + c) * DINNER + e;
        float p = P[o], s = S[o];
        P[o] = cv;
        cv = p * cv + s;
    }
    carry[idx] = cv;
}

// ---------------- phase3 fused: replay + y=(ct*st+D*u)*sig -> bf16 ------
// bt buffer is overwritten in place with ybf.
__global__ __launch_bounds__(256) void p3y_v4(
    const ushort_t* __restrict__ dec, ushort_t* __restrict__ bty,
    const ushort_t* __restrict__ ct, const ushort_t* __restrict__ ub,
    const ushort_t* __restrict__ sg, const float* __restrict__ Dp,
    const float* __restrict__ Pc, int Lc, int nsub)
{
    int t = blockIdx.x * 256 + threadIdx.x;    // BATCH*nsub*512 threads
    int e = (t & 511) << 2;
    int rest = t >> 9;
    int c = rest % nsub;
    int b = rest / nsub;
    size_t off = ((size_t)b * Lc + (size_t)c * CLS) * DINNER + e;
    size_t po = ((size_t)b * nsub + c) * DINNER + e;
    float4 stv = *(const float4*)(Pc + po);
    float4 Dv  = *(const float4*)(Dp + e);
    float st[4] = {stv.x, stv.y, stv.z, stv.w};
    float D4[4] = {Dv.x, Dv.y, Dv.z, Dv.w};
    for (int t0 = 0; t0 < CLS; ++t0) {
        size_t o = off + (size_t)t0 * DINNER;
        u16x4 d4 = *(const u16x4*)(dec + o);
        u16x4 b4 = *(const u16x4*)(bty + o);
        u16x4 c4 = *(const u16x4*)(ct + o);
        u16x4 u4 = *(const u16x4*)(ub + o);
        u16x4 g4 = *(const u16x4*)(sg + o);
        u16x4 y4;
#pragma unroll
        for (int j = 0; j < 4; ++j) {
            float d = bf2f(d4[j]);
            float u = bf2f(u4[j]);
            float inc = (1.f - d) * bf2f(b4[j]) * u;
            st[j] = d * st[j] + inc;
            float y = bf2f(c4[j]) * st[j] + D4[j] * u;
            y4[j] = f2bf(y * bf2f(g4[j]));
        }
        *(u16x4*)(bty + o) = y4;
    }
}

extern "C" void kernel_launch(void* const* d_in, const int* in_sizes, int n_in,
                              void* d_out, int out_size, void* d_ws, size_t ws_size,
                              hipStream_t stream)
{
    const float* x    = (const float*)d_in[0];
    const float* ipw  = (const float*)d_in[1];
    const float* ipb  = (const float*)d_in[2];
    const float* cw   = (const float*)d_in[3];
    const float* cb   = (const float*)d_in[4];
    const float* dtw  = (const float*)d_in[5];
    const float* dtb  = (const float*)d_in[6];
    const float* bw   = (const float*)d_in[7];
    const float* cwt  = (const float*)d_in[8];
    const float* alog = (const float*)d_in[9];
    const float* dpar = (const float*)d_in[10];
    const float* ow   = (const float*)d_in[11];
    const float* ob   = (const float*)d_in[12];
    float* out = (float*)d_out;

    const size_t XN   = (size_t)BATCH * SEQ * DMODEL;
    const size_t WIP  = (size_t)2 * DINNER * DMODEL;
    const size_t WSQ  = (size_t)DINNER * DINNER;
    const size_t WOUT = (size_t)DMODEL * DINNER;
    const size_t const_bytes = 2 * (XN + WIP + 3 * WSQ + WOUT);

    // ---- choose Lc ----
    const int cands[6] = {4096, 2048, 1024, 512, 256, 128};
    int Lc = 128;
    for (int i = 0; i < 6; ++i) {
        size_t NBe = (size_t)BATCH * cands[i] * DINNER;
        size_t need = const_bytes
                    + 5 * NBe * 2
                    + (size_t)BATCH * 3 * DINNER * 2
                    + (size_t)BATCH * DINNER * 4
                    + 2 * (size_t)BATCH * (cands[i] / CLS) * DINNER * 4
                    + 1024;
        if (need <= ws_size) { Lc = cands[i]; break; }
    }
    const int nsub = Lc / CLS;
    const size_t NBe = (size_t)BATCH * Lc * DINNER;

    // ---- workspace layout ----
    char* p = (char*)d_ws;
    ushort_t* xbf   = (ushort_t*)p; p += XN * 2;
    ushort_t* ipwbf = (ushort_t*)p; p += WIP * 2;
    ushort_t* dtwbf = (ushort_t*)p; p += WSQ * 2;
    ushort_t* bwbf  = (ushort_t*)p; p += WSQ * 2;
    ushort_t* cwtbf = (ushort_t*)p; p += WSQ * 2;
    ushort_t* owbf  = (ushort_t*)p; p += WOUT * 2;
    ushort_t* S1 = (ushort_t*)p; p += NBe * 2;   // xb -> ct
    ushort_t* S2 = (ushort_t*)p; p += NBe * 2;   // u
    ushort_t* S3 = (ushort_t*)p; p += NBe * 2;   // decay
    ushort_t* S4 = (ushort_t*)p; p += NBe * 2;   // bt -> ybf
    ushort_t* S5 = (ushort_t*)p; p += NBe * 2;   // sigmoid(z)
    ushort_t* tailb = (ushort_t*)p; p += (size_t)BATCH * 3 * DINNER * 2;
    float* carry = (float*)p; p += (size_t)BATCH * DINNER * 4;
    float* Pb    = (float*)p; p += (size_t)BATCH * nsub * DINNER * 4;
    float* Sb    = (float*)p;

    const dim3 blk(256);
    const int M = BATCH * Lc;
    const dim3 gSq(DINNER / 128, M / 128);
    const dim3 gOut(DMODEL / 128, M / 128);
    const int pwBlocks = (int)(((NBe + 255) / 256 < 4096) ? (NBe + 255) / 256 : 4096);
    const int scanBlocks = BATCH * nsub * 2;     // x4 vectorized, 512 thr/(b,c)

    auto cvt = [&](const float* in, ushort_t* outp, size_t n) {
        int n4 = (int)(n / 4);
        int g = n4 / 256 < 2048 ? (n4 + 255) / 256 : 2048;
        cvt_bf16_k<<<g, blk, 0, stream>>>((const float4*)in, (ushort4*)outp, n4);
    };
    cvt(x, xbf, XN);
    cvt(ipw, ipwbf, WIP);
    cvt(dtw, dtwbf, WSQ);
    cvt(bw, bwbf, WSQ);
    cvt(cwt, cwtbf, WSQ);
    cvt(ow, owbf, WOUT);

    const int nchunks = SEQ / Lc;
    for (int c = 0; c < nchunks; ++c) {
        const int l0 = c * Lc;
        // 1a. xb = x @ ipw[0:2048]^T + b  (bf16)
        gemm_bf16_ep<<<gSq, blk, 0, stream>>>(
            (const bf16_t*)xbf, (const bf16_t*)ipwbf, ipb,
            nullptr, S1, nullptr,
            DMODEL, DINNER, Lc, SEQ, l0, Lc, 0, EP_BF);
        // 1b. sig = sigmoid(x @ ipw[2048:4096]^T + b)
        gemm_bf16_ep<<<gSq, blk, 0, stream>>>(
            (const bf16_t*)xbf, (const bf16_t*)(ipwbf + (size_t)DINNER * DMODEL),
            ipb + DINNER, nullptr, S5, nullptr,
            DMODEL, DINNER, Lc, SEQ, l0, Lc, 0, EP_SIG);
        // 2. u = silu(conv(xb))
        conv_silu_bf<<<pwBlocks, blk, 0, stream>>>(S1, tailb, cw, cb, S2, Lc, l0, NBe);
        if (nchunks > 1)
            tail_update_bf<<<BATCH * 3 * DINNER / 256, blk, 0, stream>>>(S1, tailb, Lc);
        // 3a. decay = exp(-(softplus_poly(u@dtw+dtb)+1e-4)*A)
        gemm_bf16_ep<<<gSq, blk, 0, stream>>>(
            (const bf16_t*)S2, (const bf16_t*)dtwbf, dtb,
            nullptr, S3, alog,
            DINNER, DINNER, Lc, Lc, 0, Lc, 0, EP_DT);
        // 3b. bt = tanh_poly(u@bw)
        gemm_bf16_ep<<<gSq, blk, 0, stream>>>(
            (const bf16_t*)S2, (const bf16_t*)bwbf, nullptr,
            nullptr, S4, nullptr,
            DINNER, DINNER, Lc, Lc, 0, Lc, 0, EP_TANH);
        // 3c. ct = tanh_poly(u@cw)
        gemm_bf16_ep<<<gSq, blk, 0, stream>>>(
            (const bf16_t*)S2, (const bf16_t*)cwtbf, nullptr,
            nullptr, S1, nullptr,
            DINNER, DINNER, Lc, Lc, 0, Lc, 0, EP_TANH);
        // 4-5. scan partials + combine (inc computed on the fly)
        scan1_v4<<<scanBlocks, blk, 0, stream>>>(S3, S4, S2, Pb, Sb, Lc, nsub);
        scan_p2<<<BATCH * DINNER / 256, blk, 0, stream>>>(Pb, Sb, carry, nsub, c == 0);
        // 6. replay + y = (ct*st + D*u)*sig -> ybf (in place over S4)
        p3y_v4<<<scanBlocks, blk, 0, stream>>>(S3, S4, S1, S2, S5, dpar, Pb, Lc, nsub);
        // 7. out = ybf @ ow^T + ob  (f32)
        gemm_bf16_ep<<<gOut, blk, 0, stream>>>(
            (const bf16_t*)S4, (const bf16_t*)owbf, ob,
            out, nullptr, nullptr,
            DINNER, DMODEL, Lc, Lc, 0, SEQ, l0, EP_F32);
    }
}